// Round 1
// baseline (414.335 us; speedup 1.0000x reference)
//
#include <hip/hip_runtime.h>

// Elementwise: y = min(((x + 1) * 0.75)^2, 10.0)
// fp32 in (8192x8192 = 67,108,864 elems), fp32 out.
// Memory-bound: 512 MiB total HBM traffic -> ~85 us floor at 6.3 TB/s.
// float4 loads/stores: 16 B/lane coalescing sweet spot (G13).

__global__ __launch_bounds__(256) void ew_kernel(const float4* __restrict__ x,
                                                 float4* __restrict__ out,
                                                 int n4) {
    int i = blockIdx.x * blockDim.x + threadIdx.x;
    if (i >= n4) return;
    float4 v = x[i];
    float4 r;
    float a0 = (v.x + 1.0f) * 0.75f;
    float a1 = (v.y + 1.0f) * 0.75f;
    float a2 = (v.z + 1.0f) * 0.75f;
    float a3 = (v.w + 1.0f) * 0.75f;
    r.x = fminf(a0 * a0, 10.0f);
    r.y = fminf(a1 * a1, 10.0f);
    r.z = fminf(a2 * a2, 10.0f);
    r.w = fminf(a3 * a3, 10.0f);
    out[i] = r;
}

extern "C" void kernel_launch(void* const* d_in, const int* in_sizes, int n_in,
                              void* d_out, int out_size, void* d_ws, size_t ws_size,
                              hipStream_t stream) {
    const float* x = (const float*)d_in[0];
    float* out = (float*)d_out;
    int n = in_sizes[0];           // 67,108,864
    int n4 = n / 4;                // divisible (8192*8192 % 4 == 0)
    int block = 256;
    int grid = (n4 + block - 1) / block;
    ew_kernel<<<grid, block, 0, stream>>>((const float4*)x, (float4*)out, n4);
}